// Round 19
// baseline (141.342 us; speedup 1.0000x reference)
//
#include <hip/hip_runtime.h>
#include <stdint.h>

// Reference: X[256,256,32,32] f32 * mask, mask[b] = concat(ones(51ch),
// bernoulli(fold_in(key(101010), idx[b]), p=0.1, (205,32,32))).
// VERIFIED PRNG (r6/r8/r10-r18 pass, absmax=0): 32-bit partitionable
// threefry: elem i: (b1,b2) = threefry2x32(key, 0, i); word = b1 ^ b2;
//   keep iff word < 429496832u (exact integer form of uniform < 0.1f)
//   key = threefry2x32((0,101010),(0,idx[b]))
// idx layout: DETECTOR REQUIRED (r9 hardcoded-int64 FAILED; detector forms
// all PASSED). Rule: words 0..255; int64 iff all odd words zero.
// Perf ladder (work/wave amortization, the only working lever):
//   r6 132.3 (1q) -> r8 119.1 (2q+nt) -> r10 116.9 (4q) -> r14 116.1 (ILP)
//   -> r17 112.1 (8q) -> r18 107.8 (16q, VGPR 44, occ 40%).
// Regressions: r11 ilv-stores, r15 block-special, r16 plain-stores
// (nt stores preserve L3 for input; FETCH=131MB = L3 serves half reads).
// r19: 32 quads/thread (8 blocks/example, 8192 waves). Flat body --
// r18 showed the compiler interleaves loads/hash/stores itself under
// register pressure (VGPR 44, no spill) rather than keeping all live.
// Geometry: 65536 quads/ex; thread t in 0..2047 owns quads t + k*2048,
// k=0..31. k=0-5: all fixed-copy (max 12287 < 13056). k=6: boundary at
// t=768 (=12*64, wave-uniform). k>=7: all mem-region.

#define EX_STRIDE    262144
#define FIXED_Q      13056
#define STEP_T       2048

typedef float f32x4 __attribute__((ext_vector_type(4)));

// JAX threefry2x32 (scalar form, for fold_in): 20 rounds, inject every 4.
__device__ __forceinline__ void threefry2x32(uint32_t k0, uint32_t k1,
                                             uint32_t& x0, uint32_t& x1) {
    const uint32_t k2 = k0 ^ k1 ^ 0x1BD11BDAu;
    x0 += k0; x1 += k1;
#define TF_R(r) { x0 += x1; x1 = __builtin_rotateleft32(x1, r); x1 ^= x0; }
    TF_R(13) TF_R(15) TF_R(26) TF_R(6)
    x0 += k1; x1 += k2 + 1u;
    TF_R(17) TF_R(29) TF_R(16) TF_R(24)
    x0 += k2; x1 += k0 + 2u;
    TF_R(13) TF_R(15) TF_R(26) TF_R(6)
    x0 += k0; x1 += k1 + 3u;
    TF_R(17) TF_R(29) TF_R(16) TF_R(24)
    x0 += k1; x1 += k2 + 4u;
    TF_R(13) TF_R(15) TF_R(26) TF_R(6)
    x0 += k2; x1 += k0 + 5u;
#undef TF_R
}

// 4-way lockstep-interleaved threefry for one quad (elements e..e+3).
// Validated r14-r18 (operation-identical to the scalar form; init folds
// exact). Draw: word = x0^x1, keep iff word < 429496832u.
__device__ __forceinline__ void mask_quad4(f32x4& v, uint32_t k0, uint32_t k1,
                                           uint32_t k2, uint32_t e) {
    uint32_t a1 = e + k1;
    uint32_t b1 = a1 + 1u, c1 = a1 + 2u, d1 = a1 + 3u;
    uint32_t a0 = k0 + a1, b0 = k0 + b1, c0 = k0 + c1, d0 = k0 + d1;
    a1 = __builtin_rotateleft32(a1, 13) ^ a0;
    b1 = __builtin_rotateleft32(b1, 13) ^ b0;
    c1 = __builtin_rotateleft32(c1, 13) ^ c0;
    d1 = __builtin_rotateleft32(d1, 13) ^ d0;
#define R4(r) \
    a0 += a1; a1 = __builtin_rotateleft32(a1, r); a1 ^= a0; \
    b0 += b1; b1 = __builtin_rotateleft32(b1, r); b1 ^= b0; \
    c0 += c1; c1 = __builtin_rotateleft32(c1, r); c1 ^= c0; \
    d0 += d1; d1 = __builtin_rotateleft32(d1, r); d1 ^= d0;
#define I4(ka, kb) \
    a0 += (ka); a1 += (kb); b0 += (ka); b1 += (kb); \
    c0 += (ka); c1 += (kb); d0 += (ka); d1 += (kb);
    R4(15) R4(26) R4(6)
    I4(k1, k2 + 1u)
    R4(17) R4(29) R4(16) R4(24)
    I4(k2, k0 + 2u)
    R4(13) R4(15) R4(26) R4(6)
    I4(k0, k1 + 3u)
    R4(17) R4(29) R4(16) R4(24)
    I4(k1, k2 + 4u)
    R4(13) R4(15) R4(26) R4(6)
    I4(k2, k0 + 5u)
#undef R4
#undef I4
    v.x = ((a0 ^ a1) < 429496832u) ? v.x : 0.0f;
    v.y = ((b0 ^ b1) < 429496832u) ? v.y : 0.0f;
    v.z = ((c0 ^ c1) < 429496832u) ? v.z : 0.0f;
    v.w = ((d0 ^ d1) < 429496832u) ? v.w : 0.0f;
}

__global__ __launch_bounds__(256, 4)
void tied_dropout_kernel(const float* __restrict__ X,
                         const int* __restrict__ idx_raw,
                         float* __restrict__ out) {
    const int b = blockIdx.y;
    const int lane = threadIdx.x & 63;

    // --- barrier-free idx-layout detection (validated r11-r18) ---
    // int64 layout <=> every odd 32-bit word of words 0..255 is zero.
    const int w1 = idx_raw[lane * 4 + 1];
    const int w3 = idx_raw[lane * 4 + 3];
    const unsigned long long ball = __ballot(w1 != 0 || w3 != 0);
    const bool is_i64 = (ball == 0ull);

    // --- fold_in(base_key=(0,101010), idx[b]), SALU via readfirstlane ---
    uint32_t raw_val = (uint32_t)(is_i64 ? idx_raw[2 * b] : idx_raw[b]);
    uint32_t f0 = 0u;
    uint32_t f1 = (uint32_t)__builtin_amdgcn_readfirstlane(raw_val);
    threefry2x32(0u, 101010u, f0, f1);
    const uint32_t k0 = f0, k1 = f1;
    const uint32_t k2 = k0 ^ k1 ^ 0x1BD11BDAu;

    const int t = blockIdx.x * blockDim.x + threadIdx.x;   // 0..2047

    const size_t ex_off = (size_t)b * EX_STRIDE;
    const f32x4* __restrict__ X4 = reinterpret_cast<const f32x4*>(X + ex_off);
    f32x4* __restrict__ O4 = reinterpret_cast<f32x4*>(out + ex_off);

    f32x4 v[32];
#pragma unroll
    for (int k = 0; k < 32; ++k)
        v[k] = X4[t + k * STEP_T];

    // k=0..5: all fixed-copy (no hash). k=6: boundary at t=768 (wave-
    // uniform). k>=7: all mem-region.
    if (t + 6 * STEP_T >= FIXED_Q)
        mask_quad4(v[6], k0, k1, k2, (uint32_t)((t + 6 * STEP_T - FIXED_Q) << 2));
#pragma unroll
    for (int k = 7; k < 32; ++k)
        mask_quad4(v[k], k0, k1, k2, (uint32_t)((t + k * STEP_T - FIXED_Q) << 2));

#pragma unroll
    for (int k = 0; k < 32; ++k)
        __builtin_nontemporal_store(v[k], O4 + t + k * STEP_T);
}

extern "C" void kernel_launch(void* const* d_in, const int* in_sizes, int n_in,
                              void* d_out, int out_size, void* d_ws, size_t ws_size,
                              hipStream_t stream) {
    const float* X = (const float*)d_in[0];
    const int* idx_raw = (const int*)d_in[1];
    // d_in[2] = epoch (ignored; reference applies mask unconditionally)
    float* out = (float*)d_out;

    dim3 block(256, 1, 1);
    dim3 grid(STEP_T / 256, 256, 1);      // (8, B=256)
    tied_dropout_kernel<<<grid, block, 0, stream>>>(X, idx_raw, out);
}

// Round 20
// 107.896 us; speedup vs baseline: 1.3100x; 1.3100x over previous
//
#include <hip/hip_runtime.h>
#include <stdint.h>

// Reference: X[256,256,32,32] f32 * mask, mask[b] = concat(ones(51ch),
// bernoulli(fold_in(key(101010), idx[b]), p=0.1, (205,32,32))).
// VERIFIED PRNG (r6/r8/r10-r19 pass, absmax=0): 32-bit partitionable
// threefry: elem i: (b1,b2) = threefry2x32(key, 0, i); word = b1 ^ b2;
//   keep iff word < 429496832u (exact integer form of uniform < 0.1f)
//   key = threefry2x32((0,101010),(0,idx[b]))
// idx layout: DETECTOR REQUIRED (r9 hardcoded-int64 FAILED; detector forms
// all PASSED). Rule: words 0..255; int64 iff all odd words zero.
// FINAL perf ladder (work/wave amortization, the only working lever):
//   r6 132.3 (1q) -> r8 119.1 (2q+nt) -> r10 116.9 (4q) -> r14 116.1 (ILP)
//   -> r17 112.1 (8q) -> r18 107.8 (16q, VGPR 44) -> r19 141.3 (32q:
//   REGRESS, VGPR cap spill -> +75MB scratch HBM traffic).
// Neutral/negative axes: MLP order, nt loads, plain stores (nt stores
// preserve L3 for input), barriers, source ILP, block specialization.
// r20: exact revert to r18 (validated best, 107.8us).
// Geometry: 65536 quads/ex; thread t in 0..4095 owns quads t + k*4096,
// k=0..15. k=0-2: all fixed-copy (max 12287 < 13056). k=3: boundary at
// t=768 (=12*64, wave-uniform). k>=4: all mem-region.

#define EX_STRIDE    262144
#define FIXED_Q      13056
#define SIXT_T       4096

typedef float f32x4 __attribute__((ext_vector_type(4)));

// JAX threefry2x32 (scalar form, for fold_in): 20 rounds, inject every 4.
__device__ __forceinline__ void threefry2x32(uint32_t k0, uint32_t k1,
                                             uint32_t& x0, uint32_t& x1) {
    const uint32_t k2 = k0 ^ k1 ^ 0x1BD11BDAu;
    x0 += k0; x1 += k1;
#define TF_R(r) { x0 += x1; x1 = __builtin_rotateleft32(x1, r); x1 ^= x0; }
    TF_R(13) TF_R(15) TF_R(26) TF_R(6)
    x0 += k1; x1 += k2 + 1u;
    TF_R(17) TF_R(29) TF_R(16) TF_R(24)
    x0 += k2; x1 += k0 + 2u;
    TF_R(13) TF_R(15) TF_R(26) TF_R(6)
    x0 += k0; x1 += k1 + 3u;
    TF_R(17) TF_R(29) TF_R(16) TF_R(24)
    x0 += k1; x1 += k2 + 4u;
    TF_R(13) TF_R(15) TF_R(26) TF_R(6)
    x0 += k2; x1 += k0 + 5u;
#undef TF_R
}

// 4-way lockstep-interleaved threefry for one quad (elements e..e+3).
// Validated r14-r18 (operation-identical to the scalar form; init folds
// exact). Draw: word = x0^x1, keep iff word < 429496832u.
__device__ __forceinline__ void mask_quad4(f32x4& v, uint32_t k0, uint32_t k1,
                                           uint32_t k2, uint32_t e) {
    uint32_t a1 = e + k1;
    uint32_t b1 = a1 + 1u, c1 = a1 + 2u, d1 = a1 + 3u;
    uint32_t a0 = k0 + a1, b0 = k0 + b1, c0 = k0 + c1, d0 = k0 + d1;
    a1 = __builtin_rotateleft32(a1, 13) ^ a0;
    b1 = __builtin_rotateleft32(b1, 13) ^ b0;
    c1 = __builtin_rotateleft32(c1, 13) ^ c0;
    d1 = __builtin_rotateleft32(d1, 13) ^ d0;
#define R4(r) \
    a0 += a1; a1 = __builtin_rotateleft32(a1, r); a1 ^= a0; \
    b0 += b1; b1 = __builtin_rotateleft32(b1, r); b1 ^= b0; \
    c0 += c1; c1 = __builtin_rotateleft32(c1, r); c1 ^= c0; \
    d0 += d1; d1 = __builtin_rotateleft32(d1, r); d1 ^= d0;
#define I4(ka, kb) \
    a0 += (ka); a1 += (kb); b0 += (ka); b1 += (kb); \
    c0 += (ka); c1 += (kb); d0 += (ka); d1 += (kb);
    R4(15) R4(26) R4(6)
    I4(k1, k2 + 1u)
    R4(17) R4(29) R4(16) R4(24)
    I4(k2, k0 + 2u)
    R4(13) R4(15) R4(26) R4(6)
    I4(k0, k1 + 3u)
    R4(17) R4(29) R4(16) R4(24)
    I4(k1, k2 + 4u)
    R4(13) R4(15) R4(26) R4(6)
    I4(k2, k0 + 5u)
#undef R4
#undef I4
    v.x = ((a0 ^ a1) < 429496832u) ? v.x : 0.0f;
    v.y = ((b0 ^ b1) < 429496832u) ? v.y : 0.0f;
    v.z = ((c0 ^ c1) < 429496832u) ? v.z : 0.0f;
    v.w = ((d0 ^ d1) < 429496832u) ? v.w : 0.0f;
}

__global__ __launch_bounds__(256, 4)
void tied_dropout_kernel(const float* __restrict__ X,
                         const int* __restrict__ idx_raw,
                         float* __restrict__ out) {
    const int b = blockIdx.y;
    const int lane = threadIdx.x & 63;

    // --- barrier-free idx-layout detection (validated r11-r18) ---
    // int64 layout <=> every odd 32-bit word of words 0..255 is zero.
    const int w1 = idx_raw[lane * 4 + 1];
    const int w3 = idx_raw[lane * 4 + 3];
    const unsigned long long ball = __ballot(w1 != 0 || w3 != 0);
    const bool is_i64 = (ball == 0ull);

    // --- fold_in(base_key=(0,101010), idx[b]), SALU via readfirstlane ---
    uint32_t raw_val = (uint32_t)(is_i64 ? idx_raw[2 * b] : idx_raw[b]);
    uint32_t f0 = 0u;
    uint32_t f1 = (uint32_t)__builtin_amdgcn_readfirstlane(raw_val);
    threefry2x32(0u, 101010u, f0, f1);
    const uint32_t k0 = f0, k1 = f1;
    const uint32_t k2 = k0 ^ k1 ^ 0x1BD11BDAu;

    const int t = blockIdx.x * blockDim.x + threadIdx.x;   // 0..4095

    const size_t ex_off = (size_t)b * EX_STRIDE;
    const f32x4* __restrict__ X4 = reinterpret_cast<const f32x4*>(X + ex_off);
    f32x4* __restrict__ O4 = reinterpret_cast<f32x4*>(out + ex_off);

    // All 16 loads up front (plain: L3-friendly reads); hash; nt stores.
    f32x4 v0  = X4[t];
    f32x4 v1  = X4[t + 1 * SIXT_T];
    f32x4 v2  = X4[t + 2 * SIXT_T];
    f32x4 v3  = X4[t + 3 * SIXT_T];
    f32x4 v4  = X4[t + 4 * SIXT_T];
    f32x4 v5  = X4[t + 5 * SIXT_T];
    f32x4 v6  = X4[t + 6 * SIXT_T];
    f32x4 v7  = X4[t + 7 * SIXT_T];
    f32x4 v8  = X4[t + 8 * SIXT_T];
    f32x4 v9  = X4[t + 9 * SIXT_T];
    f32x4 v10 = X4[t + 10 * SIXT_T];
    f32x4 v11 = X4[t + 11 * SIXT_T];
    f32x4 v12 = X4[t + 12 * SIXT_T];
    f32x4 v13 = X4[t + 13 * SIXT_T];
    f32x4 v14 = X4[t + 14 * SIXT_T];
    f32x4 v15 = X4[t + 15 * SIXT_T];

    // k=0..2: all fixed-copy (no hash). k=3: boundary at t=768 (wave-
    // uniform). k>=4: all mem-region.
    if (t + 3 * SIXT_T >= FIXED_Q)
        mask_quad4(v3, k0, k1, k2, (uint32_t)((t + 3 * SIXT_T - FIXED_Q) << 2));
    mask_quad4(v4,  k0, k1, k2, (uint32_t)((t + 4 * SIXT_T - FIXED_Q) << 2));
    mask_quad4(v5,  k0, k1, k2, (uint32_t)((t + 5 * SIXT_T - FIXED_Q) << 2));
    mask_quad4(v6,  k0, k1, k2, (uint32_t)((t + 6 * SIXT_T - FIXED_Q) << 2));
    mask_quad4(v7,  k0, k1, k2, (uint32_t)((t + 7 * SIXT_T - FIXED_Q) << 2));
    mask_quad4(v8,  k0, k1, k2, (uint32_t)((t + 8 * SIXT_T - FIXED_Q) << 2));
    mask_quad4(v9,  k0, k1, k2, (uint32_t)((t + 9 * SIXT_T - FIXED_Q) << 2));
    mask_quad4(v10, k0, k1, k2, (uint32_t)((t + 10 * SIXT_T - FIXED_Q) << 2));
    mask_quad4(v11, k0, k1, k2, (uint32_t)((t + 11 * SIXT_T - FIXED_Q) << 2));
    mask_quad4(v12, k0, k1, k2, (uint32_t)((t + 12 * SIXT_T - FIXED_Q) << 2));
    mask_quad4(v13, k0, k1, k2, (uint32_t)((t + 13 * SIXT_T - FIXED_Q) << 2));
    mask_quad4(v14, k0, k1, k2, (uint32_t)((t + 14 * SIXT_T - FIXED_Q) << 2));
    mask_quad4(v15, k0, k1, k2, (uint32_t)((t + 15 * SIXT_T - FIXED_Q) << 2));

    __builtin_nontemporal_store(v0,  O4 + t);
    __builtin_nontemporal_store(v1,  O4 + t + 1 * SIXT_T);
    __builtin_nontemporal_store(v2,  O4 + t + 2 * SIXT_T);
    __builtin_nontemporal_store(v3,  O4 + t + 3 * SIXT_T);
    __builtin_nontemporal_store(v4,  O4 + t + 4 * SIXT_T);
    __builtin_nontemporal_store(v5,  O4 + t + 5 * SIXT_T);
    __builtin_nontemporal_store(v6,  O4 + t + 6 * SIXT_T);
    __builtin_nontemporal_store(v7,  O4 + t + 7 * SIXT_T);
    __builtin_nontemporal_store(v8,  O4 + t + 8 * SIXT_T);
    __builtin_nontemporal_store(v9,  O4 + t + 9 * SIXT_T);
    __builtin_nontemporal_store(v10, O4 + t + 10 * SIXT_T);
    __builtin_nontemporal_store(v11, O4 + t + 11 * SIXT_T);
    __builtin_nontemporal_store(v12, O4 + t + 12 * SIXT_T);
    __builtin_nontemporal_store(v13, O4 + t + 13 * SIXT_T);
    __builtin_nontemporal_store(v14, O4 + t + 14 * SIXT_T);
    __builtin_nontemporal_store(v15, O4 + t + 15 * SIXT_T);
}

extern "C" void kernel_launch(void* const* d_in, const int* in_sizes, int n_in,
                              void* d_out, int out_size, void* d_ws, size_t ws_size,
                              hipStream_t stream) {
    const float* X = (const float*)d_in[0];
    const int* idx_raw = (const int*)d_in[1];
    // d_in[2] = epoch (ignored; reference applies mask unconditionally)
    float* out = (float*)d_out;

    dim3 block(256, 1, 1);
    dim3 grid(SIXT_T / 256, 256, 1);      // (16, B=256)
    tied_dropout_kernel<<<grid, block, 0, stream>>>(X, idx_raw, out);
}